// Round 12
// baseline (290.972 us; speedup 1.0000x reference)
//
#include <hip/hip_runtime.h>
#include <hip/hip_bf16.h>

#define BB 8
#define NN 16384
#define DD 1024
#define AA 128

typedef __attribute__((ext_vector_type(8))) short bf16x8;
typedef __attribute__((ext_vector_type(4))) float f32x4;
typedef __attribute__((ext_vector_type(4))) unsigned short u16x4;

__device__ __forceinline__ unsigned short f2bf(float x) {
  union { __hip_bfloat16 h; unsigned short u; } cv;
  cv.h = __float2bfloat16(x);
  return cv.u;
}

__device__ __forceinline__ float softplusf(float x) {
  return fmaxf(x, 0.f) + log1pf(expf(-fabsf(x)));
}

// order-preserving float->uint map (monotone)
__device__ __forceinline__ unsigned int ordu(float x) {
  unsigned int u = __float_as_uint(x);
  return (u & 0x80000000u) ? ~u : (u | 0x80000000u);
}

// LDS index swizzle for k_select
__device__ __forceinline__ int fvx(int i) {
  return i ^ ((i >> 6) & 63);
}

// ---------------------------------------------------------------------------
// Kernel 0: W1 -> W1T (bf16, [A=128][D=1024]); zero out[8..9].
// ---------------------------------------------------------------------------
__global__ __launch_bounds__(256) void k_prep(
    const float* __restrict__ W1, unsigned short* __restrict__ W1T,
    float* __restrict__ out) {
  const int gid = blockIdx.x * 256 + threadIdx.x;
  if (gid == 0) { out[8] = 0.f; out[9] = 0.f; }
  if (gid < DD * AA) {
    const int col = gid >> 10;
    const int k   = gid & 1023;
    W1T[gid] = f2bf(W1[k * AA + col]);
  }
}

// ---------------------------------------------------------------------------
// Kernel 1 (barrier-free): wave owns 32 rows x all 128 cols.
//   A: direct global f32 loads (each X element read exactly once), cvt->bf16
//   B: direct loads from L2-resident W1T (bf16)
//   f & y epilogues: wave-local shfl reductions. No LDS, no __syncthreads.
// Fragment k-mapping identical to the R8-verified LDS path:
//   af[j] = X[row][ch*32 + lg*8 + j], bg[j] = W1T[col][ch*32 + lg*8 + j].
// ---------------------------------------------------------------------------
__global__ __launch_bounds__(256) void k_scores(
    const float* __restrict__ X, const unsigned short* __restrict__ W1T,
    const float* __restrict__ b1, const float* __restrict__ w2,
    const float* __restrict__ b2p, const float* __restrict__ Wc,
    float* __restrict__ f, float* __restrict__ y) {
  const int t = threadIdx.x;
  const int lane = t & 63;
  const int wv = t >> 6;
  const int l15 = lane & 15, lg = lane >> 4;
  const size_t row0 = (size_t)blockIdx.x * 128 + wv * 32;

  const float* Xr0 = X + (row0 + l15) * DD + lg * 8;        // rows for mi=0
  const float* Xr1 = Xr0 + (size_t)16 * DD;                 // rows for mi=1
  const unsigned short* Bp = W1T + (size_t)l15 * DD + lg * 8;
  const float* Wcp = Wc + lg * 8;

  f32x4 zero4 = {0.f, 0.f, 0.f, 0.f};
  f32x4 acc[2][8];
#pragma unroll
  for (int mi = 0; mi < 2; ++mi)
#pragma unroll
    for (int ni = 0; ni < 8; ++ni) acc[mi][ni] = zero4;
  float yp0 = 0.f, yp1 = 0.f;

#pragma unroll 2
  for (int ch = 0; ch < 32; ++ch) {
    const int koff = ch * 32;
    const float4 a0l = *(const float4*)(Xr0 + koff);
    const float4 a0h = *(const float4*)(Xr0 + koff + 4);
    const float4 a1l = *(const float4*)(Xr1 + koff);
    const float4 a1h = *(const float4*)(Xr1 + koff + 4);
    const float4 wl  = *(const float4*)(Wcp + koff);
    const float4 wh  = *(const float4*)(Wcp + koff + 4);

    yp0 += a0l.x * wl.x + a0l.y * wl.y + a0l.z * wl.z + a0l.w * wl.w +
           a0h.x * wh.x + a0h.y * wh.y + a0h.z * wh.z + a0h.w * wh.w;
    yp1 += a1l.x * wl.x + a1l.y * wl.y + a1l.z * wl.z + a1l.w * wl.w +
           a1h.x * wh.x + a1h.y * wh.y + a1h.z * wh.z + a1h.w * wh.w;

    bf16x8 af0, af1;
    af0[0] = (short)f2bf(a0l.x); af0[1] = (short)f2bf(a0l.y);
    af0[2] = (short)f2bf(a0l.z); af0[3] = (short)f2bf(a0l.w);
    af0[4] = (short)f2bf(a0h.x); af0[5] = (short)f2bf(a0h.y);
    af0[6] = (short)f2bf(a0h.z); af0[7] = (short)f2bf(a0h.w);
    af1[0] = (short)f2bf(a1l.x); af1[1] = (short)f2bf(a1l.y);
    af1[2] = (short)f2bf(a1l.z); af1[3] = (short)f2bf(a1l.w);
    af1[4] = (short)f2bf(a1h.x); af1[5] = (short)f2bf(a1h.y);
    af1[6] = (short)f2bf(a1h.z); af1[7] = (short)f2bf(a1h.w);

#pragma unroll
    for (int ni = 0; ni < 8; ++ni) {
      const bf16x8 bg = *(const bf16x8*)(Bp + (size_t)ni * 16 * DD + koff);
      acc[0][ni] = __builtin_amdgcn_mfma_f32_16x16x32_bf16(af0, bg, acc[0][ni], 0, 0, 0);
      acc[1][ni] = __builtin_amdgcn_mfma_f32_16x16x32_bf16(af1, bg, acc[1][ni], 0, 0, 0);
    }
  }

  // ---- y epilogue: reduce yp over the 4 lg-groups ----
  {
    float s0 = yp0, s1 = yp1;
    s0 += __shfl_xor(s0, 16); s0 += __shfl_xor(s0, 32);
    s1 += __shfl_xor(s1, 16); s1 += __shfl_xor(s1, 32);
    if (lg == 0) {
      y[row0 + l15] = s0;
      y[row0 + 16 + l15] = s1;
    }
  }

  // ---- f epilogue: wave-local; C layout row=lg*4+q, col=l15 ----
  const float b2 = b2p[0];
  float w2c[8], b1c[8];
#pragma unroll
  for (int ni = 0; ni < 8; ++ni) {
    w2c[ni] = w2[ni * 16 + l15];
    b1c[ni] = b1[ni * 16 + l15];
  }
#pragma unroll
  for (int mi = 0; mi < 2; ++mi) {
#pragma unroll
    for (int q = 0; q < 4; ++q) {
      float s = 0.f;
#pragma unroll
      for (int ni = 0; ni < 8; ++ni)
        s += w2c[ni] * tanhf(acc[mi][ni][q] + b1c[ni]);
      s += __shfl_xor(s, 1);
      s += __shfl_xor(s, 2);
      s += __shfl_xor(s, 4);
      s += __shfl_xor(s, 8);
      if (l15 == 0) f[row0 + mi * 16 + lg * 4 + q] = s + b2;
    }
  }
}

// ---------------------------------------------------------------------------
// Kernel 2: per bag (1 block, 1024 thr):
//  (a) masked m, Z, Sy -> bag_pred, crit_loss
//  (b) top/bottom-64 ids via 4-pass byte radix select (ties: lowest index)
// ---------------------------------------------------------------------------
__global__ __launch_bounds__(1024) void k_select(
    const float* __restrict__ f, const float* __restrict__ y,
    const float* __restrict__ mask, const int* __restrict__ labels,
    const float* __restrict__ bc, int* __restrict__ sel,
    float* __restrict__ out) {
  __shared__ unsigned int uv[NN];     // 64 KB, swizzled via fvx()
  __shared__ unsigned int hist[256];
  __shared__ unsigned int wq[16];
  __shared__ unsigned int sb[4];
  __shared__ float redf[16];
  const int t = threadIdx.x;
  const int lane = t & 63, w = t >> 6;
  const int b = blockIdx.x;
  const float* fb = f + (size_t)b * NN;
  const float* yb = y + (size_t)b * NN;
  const float* kb = mask + (size_t)b * NN;

  // load keys + masked max
  float mx = -3.0e38f;
  for (int i = t; i < NN; i += 1024) {
    const float v = fb[i];
    uv[fvx(i)] = ordu(v);
    mx = fmaxf(mx, kb[i] > 0.f ? v : -1.0e30f);
  }
#pragma unroll
  for (int s = 1; s < 64; s <<= 1) mx = fmaxf(mx, __shfl_xor(mx, s));
  if (lane == 0) redf[w] = mx;
  __syncthreads();
  float m = redf[0];
#pragma unroll
  for (int q = 1; q < 16; ++q) m = fmaxf(m, redf[q]);
  __syncthreads();

  // Z and Sy
  float se = 0.f, sy = 0.f;
  for (int i = t; i < NN; i += 1024) {
    if (kb[i] > 0.f) {
      const float e = expf(fb[i] - m);
      se += e;
      sy += e * yb[i];
    }
  }
#pragma unroll
  for (int s = 1; s < 64; s <<= 1) se += __shfl_xor(se, s);
  if (lane == 0) redf[w] = se;
  __syncthreads();
  float Z = 0.f;
#pragma unroll
  for (int q = 0; q < 16; ++q) Z += redf[q];
  __syncthreads();
#pragma unroll
  for (int s = 1; s < 64; s <<= 1) sy += __shfl_xor(sy, s);
  if (lane == 0) redf[w] = sy;
  __syncthreads();
  if (t == 0) {
    float Sy = 0.f;
#pragma unroll
    for (int q = 0; q < 16; ++q) Sy += redf[q];
    const float bp = Sy / Z + bc[0];
    out[b] = bp;
    const float lf = (float)labels[b];
    atomicAdd(out + 8, (softplusf(bp) - bp * lf) * 0.125f);
  }
  __syncthreads();

  // radix select (R7-verified)
  const int i0 = t * 16;
  for (int mode = 0; mode < 2; ++mode) {
    unsigned int pref = 0u, above = 0u, krem = 64u;
    for (int p = 3; p >= 0; --p) {
      if (t < 256) hist[t] = 0u;
      __syncthreads();
      const unsigned int pmask = (p == 3) ? 0u : (0xFFFFFFFFu << ((p + 1) * 8));
      for (int j = 0; j < 16; ++j) {
        unsigned int u = uv[fvx(i0 + j)];
        if (mode) u = ~u;
        if ((u & pmask) == pref)
          atomicAdd(&hist[(u >> (p * 8)) & 255u], 1u);
      }
      __syncthreads();
      unsigned int v = 0, s = 0;
      if (t < 256) {
        v = hist[t];
        s = v;
#pragma unroll
        for (int off = 1; off < 64; off <<= 1) {
          const unsigned int o = __shfl_down(s, off);
          if (lane + off < 64) s += o;
        }
        if (lane == 0) wq[w] = s;
      }
      __syncthreads();
      if (t < 256) {
        unsigned int hi = 0;
        for (int q = w + 1; q < 4; ++q) hi += wq[q];
        const unsigned int Ssuf = s + hi;
        const unsigned int Snext = Ssuf - v;
        if (Ssuf >= krem && Snext < krem) {
          sb[0] = pref | ((unsigned int)t << (p * 8));
          sb[1] = above + Snext;
          sb[2] = krem - Snext;
          sb[3] = 0u;
        }
      }
      __syncthreads();
      pref = sb[0]; above = sb[1]; krem = sb[2];
    }
    const int off = b * 128 + mode * 64;
    unsigned int myt = 0;
    for (int j = 0; j < 16; ++j) {
      unsigned int u = uv[fvx(i0 + j)];
      if (mode) u = ~u;
      if (u > pref) {
        const unsigned int pos = atomicAdd(&sb[3], 1u);
        sel[off + pos] = i0 + j;
      } else if (u == pref) {
        myt++;
      }
    }
    unsigned int pv = myt;
#pragma unroll
    for (int o2 = 1; o2 < 64; o2 <<= 1) {
      const unsigned int o = __shfl_up(pv, o2);
      if (lane >= o2) pv += o;
    }
    __syncthreads();
    if (lane == 63) wq[w] = pv;
    __syncthreads();
    unsigned int base = 0;
    for (int q = 0; q < w; ++q) base += wq[q];
    unsigned int gg = base + pv - myt;
    for (int j = 0; j < 16 && myt > 0; ++j) {
      unsigned int u = uv[fvx(i0 + j)];
      if (mode) u = ~u;
      if (u == pref) {
        if (gg < krem) sel[off + above + gg] = i0 + j;
        gg++;
        myt--;
      }
    }
    __syncthreads();
  }
}

// ---------------------------------------------------------------------------
// Kernel 3: instance smooth-top1-SVM losses (bag terms done in k_select).
// grid = 32 (bag = blk>>2, row-quarter = blk&3).
// ---------------------------------------------------------------------------
__global__ __launch_bounds__(256) void k_final(
    const float* __restrict__ X, const int* __restrict__ labels,
    const int* __restrict__ sel, const float* __restrict__ Wi,
    const float* __restrict__ bi, float* __restrict__ out) {
  const int b = blockIdx.x >> 2, part = blockIdx.x & 3;
  const int t = threadIdx.x;
  const int lane = t & 63, w = t >> 6;
  __shared__ float sin_[4], sout_[4];
  const int label = labels[b];

  const float* Win = Wi + label * (DD * 2);
  const float* Wot = Wi + (1 - label) * (DD * 2);
  const float bin0 = bi[label * 2], bin1 = bi[label * 2 + 1];
  const float bo0 = bi[(1 - label) * 2], bo1 = bi[(1 - label) * 2 + 1];
  float ain = 0.f, aout = 0.f;
  for (int ii = 0; ii < 8; ++ii) {
    const int r = part * 32 + w * 8 + ii;     // 0..127
    const int id = sel[b * 128 + r];
    const float* xr = X + ((size_t)b * NN + id) * DD;
    float p0 = 0.f, p1 = 0.f, p2 = 0.f, p3 = 0.f;
#pragma unroll
    for (int j = 0; j < 16; j += 4) {
      const int d = lane * 16 + j;
      const float4 x = *(const float4*)(xr + d);
      const float4 wa = *(const float4*)(Win + d * 2);
      const float4 wb = *(const float4*)(Win + d * 2 + 4);
      p0 += x.x * wa.x + x.y * wa.z + x.z * wb.x + x.w * wb.z;
      p1 += x.x * wa.y + x.y * wa.w + x.z * wb.y + x.w * wb.w;
      if (r < 64) {
        const float4 oa = *(const float4*)(Wot + d * 2);
        const float4 ob = *(const float4*)(Wot + d * 2 + 4);
        p2 += x.x * oa.x + x.y * oa.z + x.z * ob.x + x.w * ob.z;
        p3 += x.x * oa.y + x.y * oa.w + x.z * ob.y + x.w * ob.w;
      }
    }
#pragma unroll
    for (int sh = 1; sh < 64; sh <<= 1) {
      p0 += __shfl_xor(p0, sh);
      p1 += __shfl_xor(p1, sh);
      p2 += __shfl_xor(p2, sh);
      p3 += __shfl_xor(p3, sh);
    }
    if (lane == 0) {
      const float l0 = p0 + bin0, l1 = p1 + bin1;
      ain += (r < 64) ? softplusf(l0 + 1.f - l1) : softplusf(l1 + 1.f - l0);
      if (r < 64) aout += softplusf((p3 + bo1) + 1.f - (p2 + bo0));
    }
  }
  if (lane == 0) { sin_[w] = ain; sout_[w] = aout; }
  __syncthreads();
  if (t == 0) {
    const float ti = sin_[0] + sin_[1] + sin_[2] + sin_[3];
    const float to = sout_[0] + sout_[1] + sout_[2] + sout_[3];
    atomicAdd(out + 9, ti * (1.0f / 128.0f) + to * (1.0f / 64.0f));
  }
}

// ---------------------------------------------------------------------------

extern "C" void kernel_launch(void* const* d_in, const int* in_sizes, int n_in,
                              void* d_out, int out_size, void* d_ws, size_t ws_size,
                              hipStream_t stream) {
  const float* X      = (const float*)d_in[0];
  const float* mask   = (const float*)d_in[1];
  const int*   labels = (const int*)d_in[2];
  const float* W1     = (const float*)d_in[3];
  const float* b1     = (const float*)d_in[4];
  const float* w2     = (const float*)d_in[5];
  const float* b2     = (const float*)d_in[6];
  const float* Wc     = (const float*)d_in[7];
  const float* bc     = (const float*)d_in[8];
  const float* Wi     = (const float*)d_in[9];
  const float* bi     = (const float*)d_in[10];
  float* out = (float*)d_out;

  float* ws  = (float*)d_ws;
  float* f   = ws;                             // 131072 f32
  float* y   = ws + 131072;                    // 131072 f32
  int*   sel = (int*)(ws + 262144);            // 1024 int
  unsigned short* W1T = (unsigned short*)(ws + 263168);  // 131072 bf16

  k_prep  <<<512,  256, 0, stream>>>(W1, W1T, out);
  k_scores<<<1024, 256, 0, stream>>>(X, W1T, b1, w2, b2, Wc, f, y);
  k_select<<<8,   1024, 0, stream>>>(f, y, mask, labels, bc, sel, out);
  k_final <<<32,   256, 0, stream>>>(X, labels, sel, Wi, bi, out);
}

// Round 13
// 248.538 us; speedup vs baseline: 1.1707x; 1.1707x over previous
//
#include <hip/hip_runtime.h>
#include <hip/hip_bf16.h>

#define BB 8
#define NN 16384
#define DD 1024
#define AA 128
#define ROWS 64
#define NBLKS (BB * NN / ROWS)   // 2048

typedef __attribute__((ext_vector_type(8))) short bf16x8;
typedef __attribute__((ext_vector_type(4))) float f32x4;

__device__ __forceinline__ unsigned short f2bf(float x) {
  union { __hip_bfloat16 h; unsigned short u; } cv;
  cv.h = __float2bfloat16(x);
  return cv.u;
}

__device__ __forceinline__ float softplusf(float x) {
  return fmaxf(x, 0.f) + log1pf(expf(-fabsf(x)));
}

// order-preserving float->uint map (monotone)
__device__ __forceinline__ unsigned int ordu(float x) {
  unsigned int u = __float_as_uint(x);
  return (u & 0x80000000u) ? ~u : (u | 0x80000000u);
}

// LDS index swizzle for k_select
__device__ __forceinline__ int fvx(int i) {
  return i ^ ((i >> 6) & 63);
}

// async global->LDS DMA, 16 B per lane; LDS base must be wave-uniform.
__device__ __forceinline__ void gload16(const void* g, void* l) {
  __builtin_amdgcn_global_load_lds(
      (const __attribute__((address_space(1))) unsigned int*)g,
      (__attribute__((address_space(3))) unsigned int*)l, 16, 0, 0);
}

// ---------------------------------------------------------------------------
// Kernel 0: W1 -> W1Ts: bf16, 16 K-panels of [128 col][64 k], 16B-granule
// XOR-swizzled (g ^= col&7) so k_scores stages it LINEARLY via gload_lds and
// reads bank-conflict-free. Also zero out[8..9].
// ---------------------------------------------------------------------------
__global__ __launch_bounds__(256) void k_prep(
    const float* __restrict__ W1, unsigned short* __restrict__ W1Ts,
    float* __restrict__ out) {
  const int gid = blockIdx.x * 256 + threadIdx.x;
  if (gid == 0) { out[8] = 0.f; out[9] = 0.f; }
  if (gid < DD * AA) {
    const int k = gid >> 7, col = gid & 127;
    const int kp = k >> 6, kin = k & 63;
    const int g = kin >> 3, j = kin & 7;
    W1Ts[kp * 8192 + col * 64 + ((g ^ (col & 7)) << 3) + j] =
        f2bf(W1[k * AA + col]);
  }
}

// ---------------------------------------------------------------------------
// Kernel 1: f[n] = b2 + sum_a w2[a] tanh((X W1)[n][a] + b1[a]); y[n]=X[n].Wc
// 64-row tile, 4 waves (wave = 16 rows x 128 cols), K-step 64.
// T3 2-phase double-buffer: gload_lds issues step st+1 BEFORE compute(st);
// the only drain is __syncthreads at iteration end -> HBM latency hides
// under MFMA+y. A stored f32 (granule-XOR g^(row&15) via pre-swizzled global
// source), cvt->bf16 at fragment read. B staged linearly from W1Ts panels.
// ---------------------------------------------------------------------------
__global__ __launch_bounds__(256) void k_scores(
    const float* __restrict__ X, const unsigned short* __restrict__ W1Ts,
    const float* __restrict__ b1, const float* __restrict__ w2,
    const float* __restrict__ b2p, const float* __restrict__ Wc,
    float* __restrict__ f, float* __restrict__ y) {
  __shared__ float Asf[2][ROWS * 64];          // 2 x 16 KB f32
  __shared__ unsigned short Bs2[2][128 * 64];  // 2 x 16 KB bf16
  const int t = threadIdx.x;
  const int lane = t & 63, wv = t >> 6;
  const int l15 = lane & 15, lg = lane >> 4;
  const size_t row0 = (size_t)blockIdx.x * ROWS;
  const float* Xb = X + row0 * DD;

  // per-lane A-source element offsets for this wave's 4 issues (swizzled)
  int aoff[4];
#pragma unroll
  for (int q = 0; q < 4; ++q) {
    const int row = wv * 16 + q * 4 + (lane >> 4);
    const int ks = (lane & 15) ^ (row & 15);       // source 16B-granule
    aoff[q] = row * DD + ks * 4;
  }

  f32x4 zero4 = {0.f, 0.f, 0.f, 0.f};
  f32x4 acc[8];
#pragma unroll
  for (int ni = 0; ni < 8; ++ni) acc[ni] = zero4;
  float yp = 0.f;

  auto stage = [&](int buf, int stp_) {
    const int k0_ = stp_ * 64;
    const unsigned short* Pp = W1Ts + stp_ * 8192;
#pragma unroll
    for (int q = 0; q < 4; ++q) {
      gload16(Xb + aoff[q] + k0_, &Asf[buf][(wv * 4 + q) * 256]);
      gload16(Pp + ((wv * 4 + q) * 64 + lane) * 8, &Bs2[buf][(wv * 4 + q) * 512]);
    }
  };

  stage(0, 0);
  __syncthreads();

  int cur = 0;
  const int r = wv * 16 + l15;
  const int rx = r & 15;
  const int yr = wv * 16 + (lane >> 2);
  const int yrx = yr & 15;

  for (int stp = 0; stp < 16; ++stp) {
    if (stp < 15) stage(cur ^ 1, stp + 1);   // loads fly under compute below

    const float* Acur = Asf[cur];
    const unsigned short* Bcur = Bs2[cur];

    // ---- MFMA: 16 rows x 128 cols, K=64 ----
#pragma unroll
    for (int kc = 0; kc < 2; ++kc) {
      const int s0 = (kc * 4 + lg) * 2;
      const float4 alo = *(const float4*)(Acur + r * 64 + ((s0 ^ rx) << 2));
      const float4 ahi = *(const float4*)(Acur + r * 64 + (((s0 + 1) ^ rx) << 2));
      bf16x8 af;
      af[0] = (short)f2bf(alo.x); af[1] = (short)f2bf(alo.y);
      af[2] = (short)f2bf(alo.z); af[3] = (short)f2bf(alo.w);
      af[4] = (short)f2bf(ahi.x); af[5] = (short)f2bf(ahi.y);
      af[6] = (short)f2bf(ahi.z); af[7] = (short)f2bf(ahi.w);
      const int gB = kc * 4 + lg;
#pragma unroll
      for (int ni = 0; ni < 8; ++ni) {
        const int col = ni * 16 + l15;
        const bf16x8 bg =
            *(const bf16x8*)&Bcur[col * 64 + ((gB ^ (col & 7)) << 3)];
        acc[ni] = __builtin_amdgcn_mfma_f32_16x16x32_bf16(af, bg, acc[ni], 0, 0, 0);
      }
    }

    // ---- y-pass: thread covers row yr, source granules (lane&3)*4..+3 ----
    const float* yrow = Acur + yr * 64;
#pragma unroll
    for (int ss = 0; ss < 4; ++ss) {
      const int s = (lane & 3) * 4 + ss;
      const float4 v = *(const float4*)(yrow + ((s ^ yrx) << 2));
      const float4 w4 = *(const float4*)(Wc + stp * 64 + s * 4);
      yp += v.x * w4.x + v.y * w4.y + v.z * w4.z + v.w * w4.w;
    }

    __syncthreads();     // drains gload_lds (vmcnt) + ds reads -> swap safe
    cur ^= 1;
  }

  // ---- y epilogue: reduce the 4 k-quarter lanes per row ----
  yp += __shfl_xor(yp, 1);
  yp += __shfl_xor(yp, 2);
  if ((lane & 3) == 0) y[row0 + yr] = yp;

  // ---- f epilogue: C layout row=lg*4+q (within wave's 16), col=ni*16+l15 ----
  const float b2 = b2p[0];
  float w2c[8], b1c[8];
#pragma unroll
  for (int ni = 0; ni < 8; ++ni) {
    w2c[ni] = w2[ni * 16 + l15];
    b1c[ni] = b1[ni * 16 + l15];
  }
#pragma unroll
  for (int q = 0; q < 4; ++q) {
    float s = 0.f;
#pragma unroll
    for (int ni = 0; ni < 8; ++ni)
      s += w2c[ni] * tanhf(acc[ni][q] + b1c[ni]);
    s += __shfl_xor(s, 1);
    s += __shfl_xor(s, 2);
    s += __shfl_xor(s, 4);
    s += __shfl_xor(s, 8);
    if (l15 == 0) f[row0 + wv * 16 + lg * 4 + q] = s + b2;
  }
}

// ---------------------------------------------------------------------------
// Kernel 2: per bag (1 block, 1024 thr):
//  (a) masked m, Z, Sy -> bag_pred, crit_loss
//  (b) top/bottom-64 ids via 4-pass byte radix select (ties: lowest index)
// ---------------------------------------------------------------------------
__global__ __launch_bounds__(1024) void k_select(
    const float* __restrict__ f, const float* __restrict__ y,
    const float* __restrict__ mask, const int* __restrict__ labels,
    const float* __restrict__ bc, int* __restrict__ sel,
    float* __restrict__ out) {
  __shared__ unsigned int uv[NN];     // 64 KB, swizzled via fvx()
  __shared__ unsigned int hist[256];
  __shared__ unsigned int wq[16];
  __shared__ unsigned int sb[4];
  __shared__ float redf[16];
  const int t = threadIdx.x;
  const int lane = t & 63, w = t >> 6;
  const int b = blockIdx.x;
  const float* fb = f + (size_t)b * NN;
  const float* yb = y + (size_t)b * NN;
  const float* kb = mask + (size_t)b * NN;

  float mx = -3.0e38f;
  for (int i = t; i < NN; i += 1024) {
    const float v = fb[i];
    uv[fvx(i)] = ordu(v);
    mx = fmaxf(mx, kb[i] > 0.f ? v : -1.0e30f);
  }
#pragma unroll
  for (int s = 1; s < 64; s <<= 1) mx = fmaxf(mx, __shfl_xor(mx, s));
  if (lane == 0) redf[w] = mx;
  __syncthreads();
  float m = redf[0];
#pragma unroll
  for (int q = 1; q < 16; ++q) m = fmaxf(m, redf[q]);
  __syncthreads();

  float se = 0.f, sy = 0.f;
  for (int i = t; i < NN; i += 1024) {
    if (kb[i] > 0.f) {
      const float e = expf(fb[i] - m);
      se += e;
      sy += e * yb[i];
    }
  }
#pragma unroll
  for (int s = 1; s < 64; s <<= 1) se += __shfl_xor(se, s);
  if (lane == 0) redf[w] = se;
  __syncthreads();
  float Z = 0.f;
#pragma unroll
  for (int q = 0; q < 16; ++q) Z += redf[q];
  __syncthreads();
#pragma unroll
  for (int s = 1; s < 64; s <<= 1) sy += __shfl_xor(sy, s);
  if (lane == 0) redf[w] = sy;
  __syncthreads();
  if (t == 0) {
    float Sy = 0.f;
#pragma unroll
    for (int q = 0; q < 16; ++q) Sy += redf[q];
    const float bp = Sy / Z + bc[0];
    out[b] = bp;
    const float lf = (float)labels[b];
    atomicAdd(out + 8, (softplusf(bp) - bp * lf) * 0.125f);
  }
  __syncthreads();

  const int i0 = t * 16;
  for (int mode = 0; mode < 2; ++mode) {
    unsigned int pref = 0u, above = 0u, krem = 64u;
    for (int p = 3; p >= 0; --p) {
      if (t < 256) hist[t] = 0u;
      __syncthreads();
      const unsigned int pmask = (p == 3) ? 0u : (0xFFFFFFFFu << ((p + 1) * 8));
      for (int j = 0; j < 16; ++j) {
        unsigned int u = uv[fvx(i0 + j)];
        if (mode) u = ~u;
        if ((u & pmask) == pref)
          atomicAdd(&hist[(u >> (p * 8)) & 255u], 1u);
      }
      __syncthreads();
      unsigned int v = 0, s = 0;
      if (t < 256) {
        v = hist[t];
        s = v;
#pragma unroll
        for (int off = 1; off < 64; off <<= 1) {
          const unsigned int o = __shfl_down(s, off);
          if (lane + off < 64) s += o;
        }
        if (lane == 0) wq[w] = s;
      }
      __syncthreads();
      if (t < 256) {
        unsigned int hi = 0;
        for (int q = w + 1; q < 4; ++q) hi += wq[q];
        const unsigned int Ssuf = s + hi;
        const unsigned int Snext = Ssuf - v;
        if (Ssuf >= krem && Snext < krem) {
          sb[0] = pref | ((unsigned int)t << (p * 8));
          sb[1] = above + Snext;
          sb[2] = krem - Snext;
          sb[3] = 0u;
        }
      }
      __syncthreads();
      pref = sb[0]; above = sb[1]; krem = sb[2];
    }
    const int off = b * 128 + mode * 64;
    unsigned int myt = 0;
    for (int j = 0; j < 16; ++j) {
      unsigned int u = uv[fvx(i0 + j)];
      if (mode) u = ~u;
      if (u > pref) {
        const unsigned int pos = atomicAdd(&sb[3], 1u);
        sel[off + pos] = i0 + j;
      } else if (u == pref) {
        myt++;
      }
    }
    unsigned int pv = myt;
#pragma unroll
    for (int o2 = 1; o2 < 64; o2 <<= 1) {
      const unsigned int o = __shfl_up(pv, o2);
      if (lane >= o2) pv += o;
    }
    __syncthreads();
    if (lane == 63) wq[w] = pv;
    __syncthreads();
    unsigned int base = 0;
    for (int q = 0; q < w; ++q) base += wq[q];
    unsigned int gg = base + pv - myt;
    for (int j = 0; j < 16 && myt > 0; ++j) {
      unsigned int u = uv[fvx(i0 + j)];
      if (mode) u = ~u;
      if (u == pref) {
        if (gg < krem) sel[off + above + gg] = i0 + j;
        gg++;
        myt--;
      }
    }
    __syncthreads();
  }
}

// ---------------------------------------------------------------------------
// Kernel 3: instance smooth-top1-SVM losses.
// grid = 32 (bag = blk>>2, row-quarter = blk&3).
// ---------------------------------------------------------------------------
__global__ __launch_bounds__(256) void k_final(
    const float* __restrict__ X, const int* __restrict__ labels,
    const int* __restrict__ sel, const float* __restrict__ Wi,
    const float* __restrict__ bi, float* __restrict__ out) {
  const int b = blockIdx.x >> 2, part = blockIdx.x & 3;
  const int t = threadIdx.x;
  const int lane = t & 63, w = t >> 6;
  __shared__ float sin_[4], sout_[4];
  const int label = labels[b];

  const float* Win = Wi + label * (DD * 2);
  const float* Wot = Wi + (1 - label) * (DD * 2);
  const float bin0 = bi[label * 2], bin1 = bi[label * 2 + 1];
  const float bo0 = bi[(1 - label) * 2], bo1 = bi[(1 - label) * 2 + 1];
  float ain = 0.f, aout = 0.f;
  for (int ii = 0; ii < 8; ++ii) {
    const int r = part * 32 + w * 8 + ii;
    const int id = sel[b * 128 + r];
    const float* xr = X + ((size_t)b * NN + id) * DD;
    float p0 = 0.f, p1 = 0.f, p2 = 0.f, p3 = 0.f;
#pragma unroll
    for (int j = 0; j < 16; j += 4) {
      const int d = lane * 16 + j;
      const float4 x = *(const float4*)(xr + d);
      const float4 wa = *(const float4*)(Win + d * 2);
      const float4 wb = *(const float4*)(Win + d * 2 + 4);
      p0 += x.x * wa.x + x.y * wa.z + x.z * wb.x + x.w * wb.z;
      p1 += x.x * wa.y + x.y * wa.w + x.z * wb.y + x.w * wb.w;
      if (r < 64) {
        const float4 oa = *(const float4*)(Wot + d * 2);
        const float4 ob = *(const float4*)(Wot + d * 2 + 4);
        p2 += x.x * oa.x + x.y * oa.z + x.z * ob.x + x.w * ob.z;
        p3 += x.x * oa.y + x.y * oa.w + x.z * ob.y + x.w * ob.w;
      }
    }
#pragma unroll
    for (int sh = 1; sh < 64; sh <<= 1) {
      p0 += __shfl_xor(p0, sh);
      p1 += __shfl_xor(p1, sh);
      p2 += __shfl_xor(p2, sh);
      p3 += __shfl_xor(p3, sh);
    }
    if (lane == 0) {
      const float l0 = p0 + bin0, l1 = p1 + bin1;
      ain += (r < 64) ? softplusf(l0 + 1.f - l1) : softplusf(l1 + 1.f - l0);
      if (r < 64) aout += softplusf((p3 + bo1) + 1.f - (p2 + bo0));
    }
  }
  if (lane == 0) { sin_[w] = ain; sout_[w] = aout; }
  __syncthreads();
  if (t == 0) {
    const float ti = sin_[0] + sin_[1] + sin_[2] + sin_[3];
    const float to = sout_[0] + sout_[1] + sout_[2] + sout_[3];
    atomicAdd(out + 9, ti * (1.0f / 128.0f) + to * (1.0f / 64.0f));
  }
}

// ---------------------------------------------------------------------------

extern "C" void kernel_launch(void* const* d_in, const int* in_sizes, int n_in,
                              void* d_out, int out_size, void* d_ws, size_t ws_size,
                              hipStream_t stream) {
  const float* X      = (const float*)d_in[0];
  const float* mask   = (const float*)d_in[1];
  const int*   labels = (const int*)d_in[2];
  const float* W1     = (const float*)d_in[3];
  const float* b1     = (const float*)d_in[4];
  const float* w2     = (const float*)d_in[5];
  const float* b2     = (const float*)d_in[6];
  const float* Wc     = (const float*)d_in[7];
  const float* bc     = (const float*)d_in[8];
  const float* Wi     = (const float*)d_in[9];
  const float* bi     = (const float*)d_in[10];
  float* out = (float*)d_out;

  float* ws  = (float*)d_ws;
  float* f   = ws;                             // 131072 f32
  float* y   = ws + 131072;                    // 131072 f32
  int*   sel = (int*)(ws + 262144);            // 1024 int
  unsigned short* W1Ts = (unsigned short*)(ws + 263168);  // 131072 bf16

  k_prep  <<<512,   256, 0, stream>>>(W1, W1Ts, out);
  k_scores<<<NBLKS, 256, 0, stream>>>(X, W1Ts, b1, w2, b2, Wc, f, y);
  k_select<<<8,    1024, 0, stream>>>(f, y, mask, labels, bc, sel, out);
  k_final <<<32,    256, 0, stream>>>(X, labels, sel, Wi, bi, out);
}

// Round 14
// 218.385 us; speedup vs baseline: 1.3324x; 1.1381x over previous
//
#include <hip/hip_runtime.h>
#include <hip/hip_bf16.h>

#define BB 8
#define NN 16384
#define DD 1024
#define AA 128

typedef __attribute__((ext_vector_type(8))) short bf16x8;
typedef __attribute__((ext_vector_type(4))) float f32x4;
typedef __attribute__((ext_vector_type(4))) unsigned short u16x4;

__device__ __forceinline__ unsigned short f2bf(float x) {
  union { __hip_bfloat16 h; unsigned short u; } cv;
  cv.h = __float2bfloat16(x);
  return cv.u;
}

__device__ __forceinline__ float softplusf(float x) {
  return fmaxf(x, 0.f) + log1pf(expf(-fabsf(x)));
}

// order-preserving float->uint map (monotone)
__device__ __forceinline__ unsigned int ordu(float x) {
  unsigned int u = __float_as_uint(x);
  return (u & 0x80000000u) ? ~u : (u | 0x80000000u);
}

// LDS index swizzle for k_select
__device__ __forceinline__ int fvx(int i) {
  return i ^ ((i >> 6) & 63);
}

// async global->LDS DMA, 16 B per lane; LDS dest = wave-uniform base + lane*16
__device__ __forceinline__ void gload16(const void* g, void* l) {
  __builtin_amdgcn_global_load_lds(
      (const __attribute__((address_space(1))) unsigned int*)g,
      (__attribute__((address_space(3))) unsigned int*)l, 16, 0, 0);
}

// ---------------------------------------------------------------------------
// Kernel 0: W1 -> W1Ts: bf16, 16 K-panels of [128 col][64 k] whose LINEAR
// image equals R8's swizzled Bs layout (col*64 + ((ch^(col&7))<<3) + j), so
// k_scores stages each panel with plain linear gload_lds and the MFMA B-read
// path is bit-identical to R8. Also zero out[8..9].
// ---------------------------------------------------------------------------
__global__ __launch_bounds__(256) void k_prep(
    const float* __restrict__ W1, unsigned short* __restrict__ W1Ts,
    float* __restrict__ out) {
  const int gid = blockIdx.x * 256 + threadIdx.x;
  if (gid == 0) { out[8] = 0.f; out[9] = 0.f; }
  if (gid < DD * AA) {
    const int k = gid >> 7, col = gid & 127;
    const int kp = k >> 6, kin = k & 63;
    const int g = kin >> 3, j = kin & 7;
    W1Ts[kp * 8192 + col * 64 + ((g ^ (col & 7)) << 3) + j] =
        f2bf(W1[k * AA + col]);
  }
}

// ---------------------------------------------------------------------------
// Kernel 1: f[n] = b2 + sum_a w2[a] tanh((X W1)[n][a] + b1[a]);
//           y[n] = X[n,:] . Wc  (same staged registers).
// R8 structure exactly, with ONE change: B staged via global_load_lds from
// pre-swizzled W1Ts panels (linear 16 KB DMA) instead of reg+ds_write.
// ---------------------------------------------------------------------------
__global__ __launch_bounds__(256) void k_scores(
    const float* __restrict__ X, const unsigned short* __restrict__ W1Ts,
    const float* __restrict__ b1, const float* __restrict__ w2,
    const float* __restrict__ b2p, const float* __restrict__ Wc,
    float* __restrict__ f, float* __restrict__ y) {
  __shared__ unsigned short As[128 * 64];   // [row][k] bf16, swizzled
  __shared__ unsigned short Bs[128 * 64];   // [col][k] bf16, swizzled image
  __shared__ float fpart[128];
  const int t = threadIdx.x;
  const int lane = t & 63;
  const int wv = t >> 6;
  const int wr = wv >> 1, wc = wv & 1;
  const int l15 = lane & 15, lg = lane >> 4;
  const size_t row0 = (size_t)blockIdx.x * 128;
  const float* Xb = X + row0 * DD;

  f32x4 zero4 = {0.f, 0.f, 0.f, 0.f};
  f32x4 acc[4][4];
#pragma unroll
  for (int mi = 0; mi < 4; ++mi)
#pragma unroll
    for (int ni = 0; ni < 4; ++ni) acc[mi][ni] = zero4;

  float yp[8];
#pragma unroll
  for (int j = 0; j < 8; ++j) yp[j] = 0.f;

  for (int st = 0; st < 16; ++st) {
    const int k0 = st * 64;
    // ---- B: linear DMA of the pre-swizzled 16 KB panel ----
    {
      const unsigned short* Pp = W1Ts + st * 8192;
#pragma unroll
      for (int q = 0; q < 4; ++q)
        gload16(Pp + ((wv * 4 + q) * 64 + lane) * 8,
                &Bs[((wv * 4 + q) * 64 + lane) * 8]);
    }
    // ---- A: register stage f32 -> cvt -> swizzled ds_write (R8 path) ----
    const int kq = (t & 15) * 4;
    const float4 wc4 = *(const float4*)(Wc + k0 + kq);
#pragma unroll
    for (int j = 0; j < 8; ++j) {
      const int i = t + j * 256;
      const int r = i >> 4;
      float4 v = *(const float4*)(Xb + (size_t)r * DD + k0 + kq);
      yp[j] += v.x * wc4.x + v.y * wc4.y + v.z * wc4.z + v.w * wc4.w;
      u16x4 p;
      p.x = f2bf(v.x); p.y = f2bf(v.y); p.z = f2bf(v.z); p.w = f2bf(v.w);
      const int idx = r * 64 + (((kq >> 3) ^ (r & 7)) << 3) + (kq & 7);
      *(u16x4*)&As[idx] = p;
    }
    __syncthreads();
#pragma unroll
    for (int ks = 0; ks < 2; ++ks) {
      bf16x8 af[4], bg[4];
      const int chunk = ks * 4 + lg;
#pragma unroll
      for (int mi = 0; mi < 4; ++mi) {
        const int r = wr * 64 + mi * 16 + l15;
        af[mi] = *(const bf16x8*)&As[r * 64 + ((chunk ^ (r & 7)) << 3)];
      }
#pragma unroll
      for (int ni = 0; ni < 4; ++ni) {
        const int c = wc * 64 + ni * 16 + l15;
        bg[ni] = *(const bf16x8*)&Bs[c * 64 + ((chunk ^ (c & 7)) << 3)];
      }
#pragma unroll
      for (int mi = 0; mi < 4; ++mi)
#pragma unroll
        for (int ni = 0; ni < 4; ++ni)
          acc[mi][ni] = __builtin_amdgcn_mfma_f32_16x16x32_bf16(
              af[mi], bg[ni], acc[mi][ni], 0, 0, 0);
    }
    __syncthreads();
  }

  // y: reduce yp[j] across the 16 lanes sharing each row
#pragma unroll
  for (int j = 0; j < 8; ++j) {
    float s = yp[j];
    s += __shfl_xor(s, 1);
    s += __shfl_xor(s, 2);
    s += __shfl_xor(s, 4);
    s += __shfl_xor(s, 8);
    if ((t & 15) == 0) y[row0 + (t >> 4) + j * 16] = s;
  }

  // f epilogue (R1-verified)
  const float b2 = b2p[0];
  float w2c[4], b1c[4];
#pragma unroll
  for (int ni = 0; ni < 4; ++ni) {
    const int c = wc * 64 + ni * 16 + l15;
    w2c[ni] = w2[c];
    b1c[ni] = b1[c];
  }
  float pr[4][4];
#pragma unroll
  for (int mi = 0; mi < 4; ++mi) {
#pragma unroll
    for (int q = 0; q < 4; ++q) {
      float s = 0.f;
#pragma unroll
      for (int ni = 0; ni < 4; ++ni)
        s += w2c[ni] * tanhf(acc[mi][ni][q] + b1c[ni]);
      s += __shfl_xor(s, 1);
      s += __shfl_xor(s, 2);
      s += __shfl_xor(s, 4);
      s += __shfl_xor(s, 8);
      pr[mi][q] = s;
    }
  }
  if (wc == 1 && l15 == 0) {
#pragma unroll
    for (int mi = 0; mi < 4; ++mi)
#pragma unroll
      for (int q = 0; q < 4; ++q)
        fpart[wr * 64 + mi * 16 + lg * 4 + q] = pr[mi][q];
  }
  __syncthreads();
  if (wc == 0 && l15 == 0) {
#pragma unroll
    for (int mi = 0; mi < 4; ++mi)
#pragma unroll
      for (int q = 0; q < 4; ++q) {
        const int rl = wr * 64 + mi * 16 + lg * 4 + q;
        f[row0 + rl] = pr[mi][q] + fpart[rl] + b2;
      }
  }
}

// ---------------------------------------------------------------------------
// Kernel 2: per bag (1 block, 1024 thr):
//  (a) masked m, Z, Sy -> bag_pred, crit_loss
//  (b) top/bottom-64 ids via 4-pass byte radix select (ties: lowest index)
// ---------------------------------------------------------------------------
__global__ __launch_bounds__(1024) void k_select(
    const float* __restrict__ f, const float* __restrict__ y,
    const float* __restrict__ mask, const int* __restrict__ labels,
    const float* __restrict__ bc, int* __restrict__ sel,
    float* __restrict__ out) {
  __shared__ unsigned int uv[NN];     // 64 KB, swizzled via fvx()
  __shared__ unsigned int hist[256];
  __shared__ unsigned int wq[16];
  __shared__ unsigned int sb[4];
  __shared__ float redf[16];
  const int t = threadIdx.x;
  const int lane = t & 63, w = t >> 6;
  const int b = blockIdx.x;
  const float* fb = f + (size_t)b * NN;
  const float* yb = y + (size_t)b * NN;
  const float* kb = mask + (size_t)b * NN;

  // load keys + masked max
  float mx = -3.0e38f;
  for (int i = t; i < NN; i += 1024) {
    const float v = fb[i];
    uv[fvx(i)] = ordu(v);
    mx = fmaxf(mx, kb[i] > 0.f ? v : -1.0e30f);
  }
#pragma unroll
  for (int s = 1; s < 64; s <<= 1) mx = fmaxf(mx, __shfl_xor(mx, s));
  if (lane == 0) redf[w] = mx;
  __syncthreads();
  float m = redf[0];
#pragma unroll
  for (int q = 1; q < 16; ++q) m = fmaxf(m, redf[q]);
  __syncthreads();

  // Z and Sy
  float se = 0.f, sy = 0.f;
  for (int i = t; i < NN; i += 1024) {
    if (kb[i] > 0.f) {
      const float e = expf(fb[i] - m);
      se += e;
      sy += e * yb[i];
    }
  }
#pragma unroll
  for (int s = 1; s < 64; s <<= 1) se += __shfl_xor(se, s);
  if (lane == 0) redf[w] = se;
  __syncthreads();
  float Z = 0.f;
#pragma unroll
  for (int q = 0; q < 16; ++q) Z += redf[q];
  __syncthreads();
#pragma unroll
  for (int s = 1; s < 64; s <<= 1) sy += __shfl_xor(sy, s);
  if (lane == 0) redf[w] = sy;
  __syncthreads();
  if (t == 0) {
    float Sy = 0.f;
#pragma unroll
    for (int q = 0; q < 16; ++q) Sy += redf[q];
    const float bp = Sy / Z + bc[0];
    out[b] = bp;
    const float lf = (float)labels[b];
    atomicAdd(out + 8, (softplusf(bp) - bp * lf) * 0.125f);
  }
  __syncthreads();

  // radix select (R7-verified)
  const int i0 = t * 16;
  for (int mode = 0; mode < 2; ++mode) {
    unsigned int pref = 0u, above = 0u, krem = 64u;
    for (int p = 3; p >= 0; --p) {
      if (t < 256) hist[t] = 0u;
      __syncthreads();
      const unsigned int pmask = (p == 3) ? 0u : (0xFFFFFFFFu << ((p + 1) * 8));
      for (int j = 0; j < 16; ++j) {
        unsigned int u = uv[fvx(i0 + j)];
        if (mode) u = ~u;
        if ((u & pmask) == pref)
          atomicAdd(&hist[(u >> (p * 8)) & 255u], 1u);
      }
      __syncthreads();
      unsigned int v = 0, s = 0;
      if (t < 256) {
        v = hist[t];
        s = v;
#pragma unroll
        for (int off = 1; off < 64; off <<= 1) {
          const unsigned int o = __shfl_down(s, off);
          if (lane + off < 64) s += o;
        }
        if (lane == 0) wq[w] = s;
      }
      __syncthreads();
      if (t < 256) {
        unsigned int hi = 0;
        for (int q = w + 1; q < 4; ++q) hi += wq[q];
        const unsigned int Ssuf = s + hi;
        const unsigned int Snext = Ssuf - v;
        if (Ssuf >= krem && Snext < krem) {
          sb[0] = pref | ((unsigned int)t << (p * 8));
          sb[1] = above + Snext;
          sb[2] = krem - Snext;
          sb[3] = 0u;
        }
      }
      __syncthreads();
      pref = sb[0]; above = sb[1]; krem = sb[2];
    }
    const int off = b * 128 + mode * 64;
    unsigned int myt = 0;
    for (int j = 0; j < 16; ++j) {
      unsigned int u = uv[fvx(i0 + j)];
      if (mode) u = ~u;
      if (u > pref) {
        const unsigned int pos = atomicAdd(&sb[3], 1u);
        sel[off + pos] = i0 + j;
      } else if (u == pref) {
        myt++;
      }
    }
    unsigned int pv = myt;
#pragma unroll
    for (int o2 = 1; o2 < 64; o2 <<= 1) {
      const unsigned int o = __shfl_up(pv, o2);
      if (lane >= o2) pv += o;
    }
    __syncthreads();
    if (lane == 63) wq[w] = pv;
    __syncthreads();
    unsigned int base = 0;
    for (int q = 0; q < w; ++q) base += wq[q];
    unsigned int gg = base + pv - myt;
    for (int j = 0; j < 16 && myt > 0; ++j) {
      unsigned int u = uv[fvx(i0 + j)];
      if (mode) u = ~u;
      if (u == pref) {
        if (gg < krem) sel[off + above + gg] = i0 + j;
        gg++;
        myt--;
      }
    }
    __syncthreads();
  }
}

// ---------------------------------------------------------------------------
// Kernel 3: instance smooth-top1-SVM losses (bag terms done in k_select).
// grid = 32 (bag = blk>>2, row-quarter = blk&3).
// ---------------------------------------------------------------------------
__global__ __launch_bounds__(256) void k_final(
    const float* __restrict__ X, const int* __restrict__ labels,
    const int* __restrict__ sel, const float* __restrict__ Wi,
    const float* __restrict__ bi, float* __restrict__ out) {
  const int b = blockIdx.x >> 2, part = blockIdx.x & 3;
  const int t = threadIdx.x;
  const int lane = t & 63, w = t >> 6;
  __shared__ float sin_[4], sout_[4];
  const int label = labels[b];

  const float* Win = Wi + label * (DD * 2);
  const float* Wot = Wi + (1 - label) * (DD * 2);
  const float bin0 = bi[label * 2], bin1 = bi[label * 2 + 1];
  const float bo0 = bi[(1 - label) * 2], bo1 = bi[(1 - label) * 2 + 1];
  float ain = 0.f, aout = 0.f;
  for (int ii = 0; ii < 8; ++ii) {
    const int r = part * 32 + w * 8 + ii;     // 0..127
    const int id = sel[b * 128 + r];
    const float* xr = X + ((size_t)b * NN + id) * DD;
    float p0 = 0.f, p1 = 0.f, p2 = 0.f, p3 = 0.f;
#pragma unroll
    for (int j = 0; j < 16; j += 4) {
      const int d = lane * 16 + j;
      const float4 x = *(const float4*)(xr + d);
      const float4 wa = *(const float4*)(Win + d * 2);
      const float4 wb = *(const float4*)(Win + d * 2 + 4);
      p0 += x.x * wa.x + x.y * wa.z + x.z * wb.x + x.w * wb.z;
      p1 += x.x * wa.y + x.y * wa.w + x.z * wb.y + x.w * wb.w;
      if (r < 64) {
        const float4 oa = *(const float4*)(Wot + d * 2);
        const float4 ob = *(const float4*)(Wot + d * 2 + 4);
        p2 += x.x * oa.x + x.y * oa.z + x.z * ob.x + x.w * ob.z;
        p3 += x.x * oa.y + x.y * oa.w + x.z * ob.y + x.w * ob.w;
      }
    }
#pragma unroll
    for (int sh = 1; sh < 64; sh <<= 1) {
      p0 += __shfl_xor(p0, sh);
      p1 += __shfl_xor(p1, sh);
      p2 += __shfl_xor(p2, sh);
      p3 += __shfl_xor(p3, sh);
    }
    if (lane == 0) {
      const float l0 = p0 + bin0, l1 = p1 + bin1;
      ain += (r < 64) ? softplusf(l0 + 1.f - l1) : softplusf(l1 + 1.f - l0);
      if (r < 64) aout += softplusf((p3 + bo1) + 1.f - (p2 + bo0));
    }
  }
  if (lane == 0) { sin_[w] = ain; sout_[w] = aout; }
  __syncthreads();
  if (t == 0) {
    const float ti = sin_[0] + sin_[1] + sin_[2] + sin_[3];
    const float to = sout_[0] + sout_[1] + sout_[2] + sout_[3];
    atomicAdd(out + 9, ti * (1.0f / 128.0f) + to * (1.0f / 64.0f));
  }
}

// ---------------------------------------------------------------------------

extern "C" void kernel_launch(void* const* d_in, const int* in_sizes, int n_in,
                              void* d_out, int out_size, void* d_ws, size_t ws_size,
                              hipStream_t stream) {
  const float* X      = (const float*)d_in[0];
  const float* mask   = (const float*)d_in[1];
  const int*   labels = (const int*)d_in[2];
  const float* W1     = (const float*)d_in[3];
  const float* b1     = (const float*)d_in[4];
  const float* w2     = (const float*)d_in[5];
  const float* b2     = (const float*)d_in[6];
  const float* Wc     = (const float*)d_in[7];
  const float* bc     = (const float*)d_in[8];
  const float* Wi     = (const float*)d_in[9];
  const float* bi     = (const float*)d_in[10];
  float* out = (float*)d_out;

  float* ws  = (float*)d_ws;
  float* f   = ws;                             // 131072 f32
  float* y   = ws + 131072;                    // 131072 f32
  int*   sel = (int*)(ws + 262144);            // 1024 int
  unsigned short* W1Ts = (unsigned short*)(ws + 263168);  // 131072 bf16

  k_prep  <<<512,  256, 0, stream>>>(W1, W1Ts, out);
  k_scores<<<1024, 256, 0, stream>>>(X, W1Ts, b1, w2, b2, Wc, f, y);
  k_select<<<8,   1024, 0, stream>>>(f, y, mask, labels, bc, sel, out);
  k_final <<<32,   256, 0, stream>>>(X, labels, sel, Wi, bi, out);
}

// Round 15
// 207.087 us; speedup vs baseline: 1.4051x; 1.0546x over previous
//
#include <hip/hip_runtime.h>
#include <hip/hip_bf16.h>

#define BB 8
#define NN 16384
#define DD 1024
#define AA 128

typedef __attribute__((ext_vector_type(8))) short bf16x8;
typedef __attribute__((ext_vector_type(4))) float f32x4;
typedef __attribute__((ext_vector_type(4))) unsigned short u16x4;

__device__ __forceinline__ unsigned short f2bf(float x) {
  union { __hip_bfloat16 h; unsigned short u; } cv;
  cv.h = __float2bfloat16(x);
  return cv.u;
}

__device__ __forceinline__ float softplusf(float x) {
  return fmaxf(x, 0.f) + log1pf(expf(-fabsf(x)));
}

// order-preserving float->uint map (monotone)
__device__ __forceinline__ unsigned int ordu(float x) {
  unsigned int u = __float_as_uint(x);
  return (u & 0x80000000u) ? ~u : (u | 0x80000000u);
}

// LDS index swizzle for k_select
__device__ __forceinline__ int fvx(int i) {
  return i ^ ((i >> 6) & 63);
}

// async global->LDS DMA, 16 B per lane; LDS dest = wave-uniform base + lane*16
__device__ __forceinline__ void gload16(const void* g, void* l) {
  __builtin_amdgcn_global_load_lds(
      (const __attribute__((address_space(1))) unsigned int*)g,
      (__attribute__((address_space(3))) unsigned int*)l, 16, 0, 0);
}

// ---------------------------------------------------------------------------
// Kernel 0: W1 -> W1Ts bf16 panels (linear image == R8 swizzled Bs layout);
// zero out[8..9].
// ---------------------------------------------------------------------------
__global__ __launch_bounds__(256) void k_prep(
    const float* __restrict__ W1, unsigned short* __restrict__ W1Ts,
    float* __restrict__ out) {
  const int gid = blockIdx.x * 256 + threadIdx.x;
  if (gid == 0) { out[8] = 0.f; out[9] = 0.f; }
  if (gid < DD * AA) {
    const int k = gid >> 7, col = gid & 127;
    const int kp = k >> 6, kin = k & 63;
    const int g = kin >> 3, j = kin & 7;
    W1Ts[kp * 8192 + col * 64 + ((g ^ (col & 7)) << 3) + j] =
        f2bf(W1[k * AA + col]);
  }
}

// ---------------------------------------------------------------------------
// Kernel 1: f[n] = b2 + sum_a w2[a] tanh((X W1)[n][a] + b1[a]);
//           y[n] = X[n,:] . Wc   (R14 champion, unchanged)
// ---------------------------------------------------------------------------
__global__ __launch_bounds__(256) void k_scores(
    const float* __restrict__ X, const unsigned short* __restrict__ W1Ts,
    const float* __restrict__ b1, const float* __restrict__ w2,
    const float* __restrict__ b2p, const float* __restrict__ Wc,
    float* __restrict__ f, float* __restrict__ y) {
  __shared__ unsigned short As[128 * 64];   // [row][k] bf16, swizzled
  __shared__ unsigned short Bs[128 * 64];   // [col][k] bf16, swizzled image
  __shared__ float fpart[128];
  const int t = threadIdx.x;
  const int lane = t & 63;
  const int wv = t >> 6;
  const int wr = wv >> 1, wc = wv & 1;
  const int l15 = lane & 15, lg = lane >> 4;
  const size_t row0 = (size_t)blockIdx.x * 128;
  const float* Xb = X + row0 * DD;

  f32x4 zero4 = {0.f, 0.f, 0.f, 0.f};
  f32x4 acc[4][4];
#pragma unroll
  for (int mi = 0; mi < 4; ++mi)
#pragma unroll
    for (int ni = 0; ni < 4; ++ni) acc[mi][ni] = zero4;

  float yp[8];
#pragma unroll
  for (int j = 0; j < 8; ++j) yp[j] = 0.f;

  for (int st = 0; st < 16; ++st) {
    const int k0 = st * 64;
    {
      const unsigned short* Pp = W1Ts + st * 8192;
#pragma unroll
      for (int q = 0; q < 4; ++q)
        gload16(Pp + ((wv * 4 + q) * 64 + lane) * 8,
                &Bs[((wv * 4 + q) * 64 + lane) * 8]);
    }
    const int kq = (t & 15) * 4;
    const float4 wc4 = *(const float4*)(Wc + k0 + kq);
#pragma unroll
    for (int j = 0; j < 8; ++j) {
      const int i = t + j * 256;
      const int r = i >> 4;
      float4 v = *(const float4*)(Xb + (size_t)r * DD + k0 + kq);
      yp[j] += v.x * wc4.x + v.y * wc4.y + v.z * wc4.z + v.w * wc4.w;
      u16x4 p;
      p.x = f2bf(v.x); p.y = f2bf(v.y); p.z = f2bf(v.z); p.w = f2bf(v.w);
      const int idx = r * 64 + (((kq >> 3) ^ (r & 7)) << 3) + (kq & 7);
      *(u16x4*)&As[idx] = p;
    }
    __syncthreads();
#pragma unroll
    for (int ks = 0; ks < 2; ++ks) {
      bf16x8 af[4], bg[4];
      const int chunk = ks * 4 + lg;
#pragma unroll
      for (int mi = 0; mi < 4; ++mi) {
        const int r = wr * 64 + mi * 16 + l15;
        af[mi] = *(const bf16x8*)&As[r * 64 + ((chunk ^ (r & 7)) << 3)];
      }
#pragma unroll
      for (int ni = 0; ni < 4; ++ni) {
        const int c = wc * 64 + ni * 16 + l15;
        bg[ni] = *(const bf16x8*)&Bs[c * 64 + ((chunk ^ (c & 7)) << 3)];
      }
#pragma unroll
      for (int mi = 0; mi < 4; ++mi)
#pragma unroll
        for (int ni = 0; ni < 4; ++ni)
          acc[mi][ni] = __builtin_amdgcn_mfma_f32_16x16x32_bf16(
              af[mi], bg[ni], acc[mi][ni], 0, 0, 0);
    }
    __syncthreads();
  }

#pragma unroll
  for (int j = 0; j < 8; ++j) {
    float s = yp[j];
    s += __shfl_xor(s, 1);
    s += __shfl_xor(s, 2);
    s += __shfl_xor(s, 4);
    s += __shfl_xor(s, 8);
    if ((t & 15) == 0) y[row0 + (t >> 4) + j * 16] = s;
  }

  const float b2 = b2p[0];
  float w2c[4], b1c[4];
#pragma unroll
  for (int ni = 0; ni < 4; ++ni) {
    const int c = wc * 64 + ni * 16 + l15;
    w2c[ni] = w2[c];
    b1c[ni] = b1[c];
  }
  float pr[4][4];
#pragma unroll
  for (int mi = 0; mi < 4; ++mi) {
#pragma unroll
    for (int q = 0; q < 4; ++q) {
      float s = 0.f;
#pragma unroll
      for (int ni = 0; ni < 4; ++ni)
        s += w2c[ni] * tanhf(acc[mi][ni][q] + b1c[ni]);
      s += __shfl_xor(s, 1);
      s += __shfl_xor(s, 2);
      s += __shfl_xor(s, 4);
      s += __shfl_xor(s, 8);
      pr[mi][q] = s;
    }
  }
  if (wc == 1 && l15 == 0) {
#pragma unroll
    for (int mi = 0; mi < 4; ++mi)
#pragma unroll
      for (int q = 0; q < 4; ++q)
        fpart[wr * 64 + mi * 16 + lg * 4 + q] = pr[mi][q];
  }
  __syncthreads();
  if (wc == 0 && l15 == 0) {
#pragma unroll
    for (int mi = 0; mi < 4; ++mi)
#pragma unroll
      for (int q = 0; q < 4; ++q) {
        const int rl = wr * 64 + mi * 16 + lg * 4 + q;
        f[row0 + rl] = pr[mi][q] + fpart[rl] + b2;
      }
  }
}

// ---------------------------------------------------------------------------
// Kernel 2: 16 blocks = (bag b, mode). mode 0: top-64 + bag stats; mode 1:
// bottom-64 (keys stored pre-complemented). Radix select with WAVE-PRIVATE
// histograms (kills the first-pass LDS-atomic pileup on 2-3 hot buckets).
// ---------------------------------------------------------------------------
__global__ __launch_bounds__(1024) void k_select(
    const float* __restrict__ f, const float* __restrict__ y,
    const float* __restrict__ mask, const int* __restrict__ labels,
    const float* __restrict__ bc, int* __restrict__ sel,
    float* __restrict__ out) {
  __shared__ unsigned int uv[NN];          // 64 KB, swizzled via fvx()
  __shared__ unsigned int whist[16][256];  // 16 KB wave-private hists
  __shared__ unsigned int wq[4];
  __shared__ unsigned int sb[4];
  __shared__ float redf[16];
  const int t = threadIdx.x;
  const int lane = t & 63, w = t >> 6;
  const int b = blockIdx.x >> 1;
  const int mode = blockIdx.x & 1;
  const float* fb = f + (size_t)b * NN;
  const float* yb = y + (size_t)b * NN;
  const float* kb = mask + (size_t)b * NN;

  if (mode == 0) {
    // keys + masked max (+stats below)
    float mx = -3.0e38f;
    for (int i = t; i < NN; i += 1024) {
      const float v = fb[i];
      uv[fvx(i)] = ordu(v);
      mx = fmaxf(mx, kb[i] > 0.f ? v : -1.0e30f);
    }
#pragma unroll
    for (int s = 1; s < 64; s <<= 1) mx = fmaxf(mx, __shfl_xor(mx, s));
    if (lane == 0) redf[w] = mx;
    __syncthreads();
    float m = redf[0];
#pragma unroll
    for (int q = 1; q < 16; ++q) m = fmaxf(m, redf[q]);
    __syncthreads();

    float se = 0.f, sy = 0.f;
    for (int i = t; i < NN; i += 1024) {
      if (kb[i] > 0.f) {
        const float e = expf(fb[i] - m);
        se += e;
        sy += e * yb[i];
      }
    }
#pragma unroll
    for (int s = 1; s < 64; s <<= 1) se += __shfl_xor(se, s);
    if (lane == 0) redf[w] = se;
    __syncthreads();
    float Z = 0.f;
#pragma unroll
    for (int q = 0; q < 16; ++q) Z += redf[q];
    __syncthreads();
#pragma unroll
    for (int s = 1; s < 64; s <<= 1) sy += __shfl_xor(sy, s);
    if (lane == 0) redf[w] = sy;
    __syncthreads();
    if (t == 0) {
      float Sy = 0.f;
#pragma unroll
      for (int q = 0; q < 16; ++q) Sy += redf[q];
      const float bp = Sy / Z + bc[0];
      out[b] = bp;
      const float lf = (float)labels[b];
      atomicAdd(out + 8, (softplusf(bp) - bp * lf) * 0.125f);
    }
  } else {
    // bottom mode: store complemented keys (descending select then = bottom)
    for (int i = t; i < NN; i += 1024) uv[fvx(i)] = ~ordu(fb[i]);
  }
  __syncthreads();

  // 4-pass byte radix select for the 64 largest keys (ties: lowest index)
  const int i0 = t * 16;
  unsigned int pref = 0u, above = 0u, krem = 64u;
  for (int p = 3; p >= 0; --p) {
    for (int q = t; q < 4096; q += 1024) ((unsigned int*)whist)[q] = 0u;
    __syncthreads();
    const unsigned int pmask = (p == 3) ? 0u : (0xFFFFFFFFu << ((p + 1) * 8));
    for (int j = 0; j < 16; ++j) {
      const unsigned int u = uv[fvx(i0 + j)];
      if ((u & pmask) == pref)
        atomicAdd(&whist[w][(u >> (p * 8)) & 255u], 1u);
    }
    __syncthreads();
    unsigned int v = 0, s = 0;
    if (t < 256) {
#pragma unroll
      for (int q = 0; q < 16; ++q) v += whist[q][t];
      s = v;
#pragma unroll
      for (int off = 1; off < 64; off <<= 1) {
        const unsigned int o = __shfl_down(s, off);
        if (lane + off < 64) s += o;
      }
      if (lane == 0) wq[w] = s;
    }
    __syncthreads();
    if (t < 256) {
      unsigned int hi = 0;
      for (int q = w + 1; q < 4; ++q) hi += wq[q];
      const unsigned int Ssuf = s + hi;
      const unsigned int Snext = Ssuf - v;
      if (Ssuf >= krem && Snext < krem) {
        sb[0] = pref | ((unsigned int)t << (p * 8));
        sb[1] = above + Snext;
        sb[2] = krem - Snext;
        sb[3] = 0u;
      }
    }
    __syncthreads();
    pref = sb[0]; above = sb[1]; krem = sb[2];
  }
  const int off = b * 128 + mode * 64;
  unsigned int myt = 0;
  for (int j = 0; j < 16; ++j) {
    const unsigned int u = uv[fvx(i0 + j)];
    if (u > pref) {
      const unsigned int pos = atomicAdd(&sb[3], 1u);
      sel[off + pos] = i0 + j;
    } else if (u == pref) {
      myt++;
    }
  }
  unsigned int pv = myt;
#pragma unroll
  for (int o2 = 1; o2 < 64; o2 <<= 1) {
    const unsigned int o = __shfl_up(pv, o2);
    if (lane >= o2) pv += o;
  }
  __syncthreads();
  if (lane == 63) ((unsigned int*)whist)[w] = pv;   // reuse whist as wave sums
  __syncthreads();
  unsigned int base = 0;
  for (int q = 0; q < w; ++q) base += ((unsigned int*)whist)[q];
  unsigned int gg = base + pv - myt;
  for (int j = 0; j < 16 && myt > 0; ++j) {
    const unsigned int u = uv[fvx(i0 + j)];
    if (u == pref) {
      if (gg < krem) sel[off + above + gg] = i0 + j;
      gg++;
      myt--;
    }
  }
}

// ---------------------------------------------------------------------------
// Kernel 3: instance smooth-top1-SVM losses.
// grid = 32 (bag = blk>>2, row-quarter = blk&3).
// ---------------------------------------------------------------------------
__global__ __launch_bounds__(256) void k_final(
    const float* __restrict__ X, const int* __restrict__ labels,
    const int* __restrict__ sel, const float* __restrict__ Wi,
    const float* __restrict__ bi, float* __restrict__ out) {
  const int b = blockIdx.x >> 2, part = blockIdx.x & 3;
  const int t = threadIdx.x;
  const int lane = t & 63, w = t >> 6;
  __shared__ float sin_[4], sout_[4];
  const int label = labels[b];

  const float* Win = Wi + label * (DD * 2);
  const float* Wot = Wi + (1 - label) * (DD * 2);
  const float bin0 = bi[label * 2], bin1 = bi[label * 2 + 1];
  const float bo0 = bi[(1 - label) * 2], bo1 = bi[(1 - label) * 2 + 1];
  float ain = 0.f, aout = 0.f;
  for (int ii = 0; ii < 8; ++ii) {
    const int r = part * 32 + w * 8 + ii;
    const int id = sel[b * 128 + r];
    const float* xr = X + ((size_t)b * NN + id) * DD;
    float p0 = 0.f, p1 = 0.f, p2 = 0.f, p3 = 0.f;
#pragma unroll
    for (int j = 0; j < 16; j += 4) {
      const int d = lane * 16 + j;
      const float4 x = *(const float4*)(xr + d);
      const float4 wa = *(const float4*)(Win + d * 2);
      const float4 wb = *(const float4*)(Win + d * 2 + 4);
      p0 += x.x * wa.x + x.y * wa.z + x.z * wb.x + x.w * wb.z;
      p1 += x.x * wa.y + x.y * wa.w + x.z * wb.y + x.w * wb.w;
      if (r < 64) {
        const float4 oa = *(const float4*)(Wot + d * 2);
        const float4 ob = *(const float4*)(Wot + d * 2 + 4);
        p2 += x.x * oa.x + x.y * oa.z + x.z * ob.x + x.w * ob.z;
        p3 += x.x * oa.y + x.y * oa.w + x.z * ob.y + x.w * ob.w;
      }
    }
#pragma unroll
    for (int sh = 1; sh < 64; sh <<= 1) {
      p0 += __shfl_xor(p0, sh);
      p1 += __shfl_xor(p1, sh);
      p2 += __shfl_xor(p2, sh);
      p3 += __shfl_xor(p3, sh);
    }
    if (lane == 0) {
      const float l0 = p0 + bin0, l1 = p1 + bin1;
      ain += (r < 64) ? softplusf(l0 + 1.f - l1) : softplusf(l1 + 1.f - l0);
      if (r < 64) aout += softplusf((p3 + bo1) + 1.f - (p2 + bo0));
    }
  }
  if (lane == 0) { sin_[w] = ain; sout_[w] = aout; }
  __syncthreads();
  if (t == 0) {
    const float ti = sin_[0] + sin_[1] + sin_[2] + sin_[3];
    const float to = sout_[0] + sout_[1] + sout_[2] + sout_[3];
    atomicAdd(out + 9, ti * (1.0f / 128.0f) + to * (1.0f / 64.0f));
  }
}

// ---------------------------------------------------------------------------

extern "C" void kernel_launch(void* const* d_in, const int* in_sizes, int n_in,
                              void* d_out, int out_size, void* d_ws, size_t ws_size,
                              hipStream_t stream) {
  const float* X      = (const float*)d_in[0];
  const float* mask   = (const float*)d_in[1];
  const int*   labels = (const int*)d_in[2];
  const float* W1     = (const float*)d_in[3];
  const float* b1     = (const float*)d_in[4];
  const float* w2     = (const float*)d_in[5];
  const float* b2     = (const float*)d_in[6];
  const float* Wc     = (const float*)d_in[7];
  const float* bc     = (const float*)d_in[8];
  const float* Wi     = (const float*)d_in[9];
  const float* bi     = (const float*)d_in[10];
  float* out = (float*)d_out;

  float* ws  = (float*)d_ws;
  float* f   = ws;                             // 131072 f32
  float* y   = ws + 131072;                    // 131072 f32
  int*   sel = (int*)(ws + 262144);            // 1024 int
  unsigned short* W1Ts = (unsigned short*)(ws + 263168);  // 131072 bf16

  k_prep  <<<512,  256, 0, stream>>>(W1, W1Ts, out);
  k_scores<<<1024, 256, 0, stream>>>(X, W1Ts, b1, w2, b2, Wc, f, y);
  k_select<<<16,  1024, 0, stream>>>(f, y, mask, labels, bc, sel, out);
  k_final <<<32,   256, 0, stream>>>(X, labels, sel, Wi, bi, out);
}

// Round 16
// 182.118 us; speedup vs baseline: 1.5977x; 1.1371x over previous
//
#include <hip/hip_runtime.h>
#include <hip/hip_bf16.h>

#define BB 8
#define NN 16384
#define DD 1024
#define AA 128
#define ROWS 64
#define NBLKS (BB * NN / ROWS)   // 2048

typedef __attribute__((ext_vector_type(8))) short bf16x8;
typedef __attribute__((ext_vector_type(4))) float f32x4;
typedef __attribute__((ext_vector_type(4))) unsigned short u16x4;

__device__ __forceinline__ unsigned short f2bf(float x) {
  union { __hip_bfloat16 h; unsigned short u; } cv;
  cv.h = __float2bfloat16(x);
  return cv.u;
}

__device__ __forceinline__ float softplusf(float x) {
  return fmaxf(x, 0.f) + log1pf(expf(-fabsf(x)));
}

// order-preserving float->uint map (monotone)
__device__ __forceinline__ unsigned int ordu(float x) {
  unsigned int u = __float_as_uint(x);
  return (u & 0x80000000u) ? ~u : (u | 0x80000000u);
}

// LDS index swizzle for k_select
__device__ __forceinline__ int fvx(int i) {
  return i ^ ((i >> 6) & 63);
}

// async global->LDS DMA, 16 B per lane; dest resolves to wave base + lane*16
__device__ __forceinline__ void gload16(const void* g, void* l) {
  __builtin_amdgcn_global_load_lds(
      (const __attribute__((address_space(1))) unsigned int*)g,
      (__attribute__((address_space(3))) unsigned int*)l, 16, 0, 0);
}

// ---------------------------------------------------------------------------
// Kernel 0: W1 -> W1Ts bf16 panels (linear image == swizzled Bs layout);
// zero out[8..9].
// ---------------------------------------------------------------------------
__global__ __launch_bounds__(256) void k_prep(
    const float* __restrict__ W1, unsigned short* __restrict__ W1Ts,
    float* __restrict__ out) {
  const int gid = blockIdx.x * 256 + threadIdx.x;
  if (gid == 0) { out[8] = 0.f; out[9] = 0.f; }
  if (gid < DD * AA) {
    const int k = gid >> 7, col = gid & 127;
    const int kp = k >> 6, kin = k & 63;
    const int g = kin >> 3, j = kin & 7;
    W1Ts[kp * 8192 + col * 64 + ((g ^ (col & 7)) << 3) + j] =
        f2bf(W1[k * AA + col]);
  }
}

// ---------------------------------------------------------------------------
// Kernel 1: f[n] = b2 + sum_a w2[a] tanh((X W1)[n][a] + b1[a]); y[n]=X[n].Wc
// 64-row tile (grid 2048): LDS 24 KB -> more resident blocks/CU than R14's
// 128-row tile; wave = 16 rows x 128 cols (R12-verified epilogue form).
// B staged via linear gload_lds of pre-swizzled panels (R14-verified).
// ---------------------------------------------------------------------------
__global__ __launch_bounds__(256) void k_scores(
    const float* __restrict__ X, const unsigned short* __restrict__ W1Ts,
    const float* __restrict__ b1, const float* __restrict__ w2,
    const float* __restrict__ b2p, const float* __restrict__ Wc,
    float* __restrict__ f, float* __restrict__ y) {
  __shared__ unsigned short As[ROWS * 64];   // 8 KB, [row][k] bf16 swizzled
  __shared__ unsigned short Bs[128 * 64];    // 16 KB, [col][k] swizzled image
  const int t = threadIdx.x;
  const int lane = t & 63;
  const int wv = t >> 6;
  const int l15 = lane & 15, lg = lane >> 4;
  const size_t row0 = (size_t)blockIdx.x * ROWS;
  const float* Xb = X + row0 * DD;

  f32x4 zero4 = {0.f, 0.f, 0.f, 0.f};
  f32x4 acc[8];
#pragma unroll
  for (int ni = 0; ni < 8; ++ni) acc[ni] = zero4;

  float yp[4];
#pragma unroll
  for (int j = 0; j < 4; ++j) yp[j] = 0.f;

  for (int st = 0; st < 16; ++st) {
    const int k0 = st * 64;
    // ---- B: linear DMA of the pre-swizzled 16 KB panel ----
    {
      const unsigned short* Pp = W1Ts + st * 8192;
#pragma unroll
      for (int q = 0; q < 4; ++q)
        gload16(Pp + ((wv * 4 + q) * 64 + lane) * 8,
                &Bs[((wv * 4 + q) * 64 + lane) * 8]);
    }
    // ---- A: register stage f32 -> cvt -> swizzled ds_write ----
    const int kq = (t & 15) * 4;
    const float4 wc4 = *(const float4*)(Wc + k0 + kq);
#pragma unroll
    for (int j = 0; j < 4; ++j) {
      const int i = t + j * 256;
      const int r = i >> 4;                  // 0..63
      float4 v = *(const float4*)(Xb + (size_t)r * DD + k0 + kq);
      yp[j] += v.x * wc4.x + v.y * wc4.y + v.z * wc4.z + v.w * wc4.w;
      u16x4 p;
      p.x = f2bf(v.x); p.y = f2bf(v.y); p.z = f2bf(v.z); p.w = f2bf(v.w);
      const int idx = r * 64 + (((kq >> 3) ^ (r & 7)) << 3) + (kq & 7);
      *(u16x4*)&As[idx] = p;
    }
    __syncthreads();
    // ---- MFMA: wave covers rows wv*16..+15 x all 128 cols ----
    const int r = wv * 16 + l15;
    const int rx = r & 7;
#pragma unroll
    for (int ks = 0; ks < 2; ++ks) {
      const int chunk = ks * 4 + lg;
      const bf16x8 af = *(const bf16x8*)&As[r * 64 + ((chunk ^ rx) << 3)];
#pragma unroll
      for (int ni = 0; ni < 8; ++ni) {
        const int c = ni * 16 + l15;
        const bf16x8 bg =
            *(const bf16x8*)&Bs[c * 64 + ((chunk ^ (c & 7)) << 3)];
        acc[ni] = __builtin_amdgcn_mfma_f32_16x16x32_bf16(af, bg, acc[ni], 0, 0, 0);
      }
    }
    __syncthreads();
  }

  // y: reduce yp[j] across the 16 lanes sharing each row
#pragma unroll
  for (int j = 0; j < 4; ++j) {
    float s = yp[j];
    s += __shfl_xor(s, 1);
    s += __shfl_xor(s, 2);
    s += __shfl_xor(s, 4);
    s += __shfl_xor(s, 8);
    if ((t & 15) == 0) y[row0 + (t >> 4) + j * 16] = s;
  }

  // f epilogue: wave-local; C row = lg*4+q (global wv*16+...), col = ni*16+l15
  const float b2 = b2p[0];
  float w2c[8], b1c[8];
#pragma unroll
  for (int ni = 0; ni < 8; ++ni) {
    w2c[ni] = w2[ni * 16 + l15];
    b1c[ni] = b1[ni * 16 + l15];
  }
#pragma unroll
  for (int q = 0; q < 4; ++q) {
    float s = 0.f;
#pragma unroll
    for (int ni = 0; ni < 8; ++ni)
      s += w2c[ni] * tanhf(acc[ni][q] + b1c[ni]);
    s += __shfl_xor(s, 1);
    s += __shfl_xor(s, 2);
    s += __shfl_xor(s, 4);
    s += __shfl_xor(s, 8);
    if (l15 == 0) f[row0 + wv * 16 + lg * 4 + q] = s + b2;
  }
}

// ---------------------------------------------------------------------------
// Kernel 2 (fused select+final): 16 blocks = (bag b, mode).
//   mode 0: bag stats (bag_pred, crit_loss) + top-64 + top-in + out losses
//   mode 1: bottom-64 + bottom-in losses
// Radix select with wave-private histograms; selected ids kept in LDS.
// ---------------------------------------------------------------------------
__global__ __launch_bounds__(1024) void k_select(
    const float* __restrict__ f, const float* __restrict__ y,
    const float* __restrict__ mask, const int* __restrict__ labels,
    const float* __restrict__ bc, const float* __restrict__ X,
    const float* __restrict__ Wi, const float* __restrict__ bi,
    float* __restrict__ out) {
  __shared__ unsigned int uv[NN];          // 64 KB, swizzled via fvx()
  __shared__ unsigned int whist[16][256];  // 16 KB wave-private hists
  __shared__ unsigned int selL[64];
  __shared__ unsigned int wq[4];
  __shared__ unsigned int sb[4];
  __shared__ float redf[16];
  __shared__ float redo[16];
  const int t = threadIdx.x;
  const int lane = t & 63, w = t >> 6;
  const int b = blockIdx.x >> 1;
  const int mode = blockIdx.x & 1;
  const float* fb = f + (size_t)b * NN;
  const float* yb = y + (size_t)b * NN;
  const float* kb = mask + (size_t)b * NN;

  if (mode == 0) {
    float mx = -3.0e38f;
    for (int i = t; i < NN; i += 1024) {
      const float v = fb[i];
      uv[fvx(i)] = ordu(v);
      mx = fmaxf(mx, kb[i] > 0.f ? v : -1.0e30f);
    }
#pragma unroll
    for (int s = 1; s < 64; s <<= 1) mx = fmaxf(mx, __shfl_xor(mx, s));
    if (lane == 0) redf[w] = mx;
    __syncthreads();
    float m = redf[0];
#pragma unroll
    for (int q = 1; q < 16; ++q) m = fmaxf(m, redf[q]);
    __syncthreads();

    float se = 0.f, sy = 0.f;
    for (int i = t; i < NN; i += 1024) {
      if (kb[i] > 0.f) {
        const float e = expf(fb[i] - m);
        se += e;
        sy += e * yb[i];
      }
    }
#pragma unroll
    for (int s = 1; s < 64; s <<= 1) se += __shfl_xor(se, s);
    if (lane == 0) redf[w] = se;
    __syncthreads();
    float Z = 0.f;
#pragma unroll
    for (int q = 0; q < 16; ++q) Z += redf[q];
    __syncthreads();
#pragma unroll
    for (int s = 1; s < 64; s <<= 1) sy += __shfl_xor(sy, s);
    if (lane == 0) redf[w] = sy;
    __syncthreads();
    if (t == 0) {
      float Sy = 0.f;
#pragma unroll
      for (int q = 0; q < 16; ++q) Sy += redf[q];
      const float bp = Sy / Z + bc[0];
      out[b] = bp;
      const float lf = (float)labels[b];
      atomicAdd(out + 8, (softplusf(bp) - bp * lf) * 0.125f);
    }
  } else {
    for (int i = t; i < NN; i += 1024) uv[fvx(i)] = ~ordu(fb[i]);
  }
  __syncthreads();

  // 4-pass byte radix select for the 64 largest keys (ties: lowest index)
  const int i0 = t * 16;
  unsigned int pref = 0u, above = 0u, krem = 64u;
  for (int p = 3; p >= 0; --p) {
    for (int q = t; q < 4096; q += 1024) ((unsigned int*)whist)[q] = 0u;
    __syncthreads();
    const unsigned int pmask = (p == 3) ? 0u : (0xFFFFFFFFu << ((p + 1) * 8));
    for (int j = 0; j < 16; ++j) {
      const unsigned int u = uv[fvx(i0 + j)];
      if ((u & pmask) == pref)
        atomicAdd(&whist[w][(u >> (p * 8)) & 255u], 1u);
    }
    __syncthreads();
    unsigned int v = 0, s = 0;
    if (t < 256) {
#pragma unroll
      for (int q = 0; q < 16; ++q) v += whist[q][t];
      s = v;
#pragma unroll
      for (int off = 1; off < 64; off <<= 1) {
        const unsigned int o = __shfl_down(s, off);
        if (lane + off < 64) s += o;
      }
      if (lane == 0) wq[w] = s;
    }
    __syncthreads();
    if (t < 256) {
      unsigned int hi = 0;
      for (int q = w + 1; q < 4; ++q) hi += wq[q];
      const unsigned int Ssuf = s + hi;
      const unsigned int Snext = Ssuf - v;
      if (Ssuf >= krem && Snext < krem) {
        sb[0] = pref | ((unsigned int)t << (p * 8));
        sb[1] = above + Snext;
        sb[2] = krem - Snext;
        sb[3] = 0u;
      }
    }
    __syncthreads();
    pref = sb[0]; above = sb[1]; krem = sb[2];
  }
  unsigned int myt = 0;
  for (int j = 0; j < 16; ++j) {
    const unsigned int u = uv[fvx(i0 + j)];
    if (u > pref) {
      const unsigned int pos = atomicAdd(&sb[3], 1u);
      selL[pos] = i0 + j;
    } else if (u == pref) {
      myt++;
    }
  }
  unsigned int pv = myt;
#pragma unroll
  for (int o2 = 1; o2 < 64; o2 <<= 1) {
    const unsigned int o = __shfl_up(pv, o2);
    if (lane >= o2) pv += o;
  }
  __syncthreads();
  if (lane == 63) ((unsigned int*)whist)[w] = pv;   // reuse whist
  __syncthreads();
  unsigned int base = 0;
  for (int q = 0; q < w; ++q) base += ((unsigned int*)whist)[q];
  unsigned int gg = base + pv - myt;
  for (int j = 0; j < 16 && myt > 0; ++j) {
    const unsigned int u = uv[fvx(i0 + j)];
    if (u == pref) {
      if (gg < krem) selL[above + gg] = i0 + j;
      gg++;
      myt--;
    }
  }
  __syncthreads();

  // ---- fused instance losses for this block's 64 rows ----
  const int label = labels[b];
  const float* Win = Wi + label * (DD * 2);
  const float* Wot = Wi + (1 - label) * (DD * 2);
  const float bin0 = bi[label * 2], bin1 = bi[label * 2 + 1];
  const float bo0 = bi[(1 - label) * 2], bo1 = bi[(1 - label) * 2 + 1];
  float ain = 0.f, aout = 0.f;
  for (int rr = w; rr < 64; rr += 16) {     // 4 rows per wave
    const int id = selL[rr];
    const float* xr = X + ((size_t)b * NN + id) * DD;
    float p0 = 0.f, p1 = 0.f, p2 = 0.f, p3 = 0.f;
#pragma unroll
    for (int j = 0; j < 16; j += 4) {
      const int d = lane * 16 + j;
      const float4 x = *(const float4*)(xr + d);
      const float4 wa = *(const float4*)(Win + d * 2);
      const float4 wb = *(const float4*)(Win + d * 2 + 4);
      p0 += x.x * wa.x + x.y * wa.z + x.z * wb.x + x.w * wb.z;
      p1 += x.x * wa.y + x.y * wa.w + x.z * wb.y + x.w * wb.w;
      if (mode == 0) {
        const float4 oa = *(const float4*)(Wot + d * 2);
        const float4 ob = *(const float4*)(Wot + d * 2 + 4);
        p2 += x.x * oa.x + x.y * oa.z + x.z * ob.x + x.w * ob.z;
        p3 += x.x * oa.y + x.y * oa.w + x.z * ob.y + x.w * ob.w;
      }
    }
#pragma unroll
    for (int sh = 1; sh < 64; sh <<= 1) {
      p0 += __shfl_xor(p0, sh);
      p1 += __shfl_xor(p1, sh);
      p2 += __shfl_xor(p2, sh);
      p3 += __shfl_xor(p3, sh);
    }
    if (lane == 0) {
      const float l0 = p0 + bin0, l1 = p1 + bin1;
      if (mode == 0) {
        ain += softplusf(l0 + 1.f - l1);              // top, target 1
        aout += softplusf((p3 + bo1) + 1.f - (p2 + bo0));  // out, target 0
      } else {
        ain += softplusf(l1 + 1.f - l0);              // bottom, target 0
      }
    }
  }
  if (lane == 0) { redf[w] = ain; redo[w] = aout; }
  __syncthreads();
  if (t == 0) {
    float ti = 0.f, to = 0.f;
#pragma unroll
    for (int q = 0; q < 16; ++q) { ti += redf[q]; to += redo[q]; }
    atomicAdd(out + 9, ti * (1.0f / 128.0f) + to * (1.0f / 64.0f));
  }
}

// ---------------------------------------------------------------------------

extern "C" void kernel_launch(void* const* d_in, const int* in_sizes, int n_in,
                              void* d_out, int out_size, void* d_ws, size_t ws_size,
                              hipStream_t stream) {
  const float* X      = (const float*)d_in[0];
  const float* mask   = (const float*)d_in[1];
  const int*   labels = (const int*)d_in[2];
  const float* W1     = (const float*)d_in[3];
  const float* b1     = (const float*)d_in[4];
  const float* w2     = (const float*)d_in[5];
  const float* b2     = (const float*)d_in[6];
  const float* Wc     = (const float*)d_in[7];
  const float* bc     = (const float*)d_in[8];
  const float* Wi     = (const float*)d_in[9];
  const float* bi     = (const float*)d_in[10];
  float* out = (float*)d_out;

  float* ws  = (float*)d_ws;
  float* f   = ws;                             // 131072 f32
  float* y   = ws + 131072;                    // 131072 f32
  unsigned short* W1Ts = (unsigned short*)(ws + 262144);  // 131072 bf16

  k_prep  <<<512,   256, 0, stream>>>(W1, W1Ts, out);
  k_scores<<<NBLKS, 256, 0, stream>>>(X, W1Ts, b1, w2, b2, Wc, f, y);
  k_select<<<16,   1024, 0, stream>>>(f, y, mask, labels, bc, X, Wi, bi, out);
}